// Round 16
// baseline (406.534 us; speedup 1.0000x reference)
//
#include <hip/hip_runtime.h>
#include <hip/hip_bf16.h>
#include <hip/hip_fp8.h>
#include <math.h>

#define AS1 __attribute__((address_space(1)))
#define AS3 __attribute__((address_space(3)))

typedef __bf16 bf16x8 __attribute__((ext_vector_type(8)));
typedef __bf16 bf16x4 __attribute__((ext_vector_type(4)));
typedef float  f32x4  __attribute__((ext_vector_type(4)));
typedef long   longx2 __attribute__((ext_vector_type(2)));

static constexpr int   N_ROWS   = 10000;
static constexpr int   D        = 256;           // K for all GEMMs
static constexpr float INV_TAU  = 2.0f;          // 1/0.5

// gram tiling: 128x128 tiles, rows padded to 10112
static constexpr int   T        = 79;            // ceil(10000/128)
static constexpr int   NP       = T * 128;       // 10112
static constexpr float PADF     = 112.0f;        // NP - N_ROWS (exp(0)=1 each)
static constexpr int   SPR     = 10;             // strips per row (ceil(79/8))
static constexpr int   BPJ     = T * SPR;        // 790 strip-blocks per job
static constexpr int   NWGG    = 5 * BPJ;        // 3950

// proj tiling (128x128 structure)
static constexpr int   PT       = 79;

// ---------------------------------------------------------------------------
// 128x128 tile GEMM helper (projection GEMMs only, bf16). K=256, BK=64,
// single-buffer, XOR-swizzled LDS via pre-swizzled global_load_lds source.
// ---------------------------------------------------------------------------
__device__ __forceinline__ void tile_gemm_128(
    const __bf16* __restrict__ Abase, const __bf16* __restrict__ Bbase,
    char* ldsA, char* ldsB, int tid, f32x4 acc[4][4])
{
  const int l      = tid & 63;
  const int wr     = (tid >> 7) & 1;
  const int wc     = (tid >> 6) & 1;
  const int srow   = tid >> 3;
  const int schunk = tid & 7;
  const int lrow   = l & 15;
  const int lk     = l >> 4;

  for (int kt = 0; kt < 4; ++kt) {
    __syncthreads();
    const int kbase = kt * 64;
#pragma unroll
    for (int rr = 0; rr < 4; ++rr) {
      const int row = rr * 32 + srow;
      const int lc  = schunk ^ (row & 7);
      const __bf16* ga = Abase + (size_t)row * D + kbase + lc * 8;
      const __bf16* gb = Bbase + (size_t)row * D + kbase + lc * 8;
      __builtin_amdgcn_global_load_lds((const AS1 void*)ga,
          (AS3 void*)(ldsA + rr * 4096 + tid * 16), 16, 0, 0);
      __builtin_amdgcn_global_load_lds((const AS1 void*)gb,
          (AS3 void*)(ldsB + rr * 4096 + tid * 16), 16, 0, 0);
    }
    __syncthreads();
#pragma unroll
    for (int ks = 0; ks < 2; ++ks) {
      bf16x8 af[4], bfr[4];
#pragma unroll
      for (int m = 0; m < 4; ++m) {
        const int row = wr * 64 + m * 16 + lrow;
        const int off = row * 128 + ((ks * 64 + lk * 16) ^ ((row & 7) << 4));
        af[m] = *(const bf16x8*)(ldsA + off);
      }
#pragma unroll
      for (int n = 0; n < 4; ++n) {
        const int row = wc * 64 + n * 16 + lrow;
        const int off = row * 128 + ((ks * 64 + lk * 16) ^ ((row & 7) << 4));
        bfr[n] = *(const bf16x8*)(ldsB + off);
      }
#pragma unroll
      for (int m = 0; m < 4; ++m)
#pragma unroll
        for (int n = 0; n < 4; ++n)
          acc[m][n] = __builtin_amdgcn_mfma_f32_16x16x32_bf16(
              af[m], bfr[n], acc[m][n], 0, 0, 0);
    }
  }
}

// ---------------------------------------------------------------------------
// Gram kernel, strip-mined, FP8 (e4m3), A MOSTLY IN REGISTERS (3/4 kt-slabs).
// r13 (A all-LDS): 3 blocks/CU, LDS 40KB/step, 86% LDS-busy -> 181 us.
// r15 (A all-regs): LDS 24KB/step but 172 unified regs/wave -> only 2
// blocks/CU -> latency-exposed -> 200 us. This round: afr holds kt=0..2
// (48 VGPR); kt=3 fragments are read from the persistent LDS A-panel each
// tile (+1KB/step). Unified demand ~156 <= 168 -> 3 blocks/CU AND 25KB/step.
// k-permutation trick (r13): MFMA sub-step sub, lane lk consumes global
// 8B-slot (2*lk+sub) for both A and B; one b128 read feeds both sub-steps.
// B double-buffered at BK=64 (2x8 KiB). LDS total 48 KiB.
// ---------------------------------------------------------------------------
__global__ __launch_bounds__(256, 3) void gram_kernel(
    const unsigned char* __restrict__ p1, const unsigned char* __restrict__ p2,
    const unsigned char* __restrict__ p3, float* __restrict__ S)
{
  const int bid = blockIdx.x;
  const int job = bid / BPJ;
  const int t0  = bid % BPJ;
  const int r   = t0 / SPR;
  const int s   = t0 % SPR;
  int cstart = s * 8;
  const int cend = min(cstart + 8, T);

  const unsigned char *P, *Q;
  float *Srow, *Scol;
  bool sym = false;
  if (job == 0)      { P = p1; Q = p2; Srow = S + 1 * NP; Scol = S + 3 * NP; }
  else if (job == 1) { P = p1; Q = p3; Srow = S + 2 * NP; Scol = nullptr; }
  else if (job == 2) { P = p2; Q = p3; Srow = S + 5 * NP; Scol = nullptr; }
  else if (job == 3) { P = p1; Q = p1; Srow = S + 0 * NP; Scol = S + 0 * NP;
                       sym = true; cstart = max(cstart, r); }
  else               { P = p2; Q = p2; Srow = S + 4 * NP; Scol = S + 4 * NP;
                       sym = true; cstart = max(cstart, r); }
  const int len = cend - cstart;
  if (len <= 0) return;
  const int nsteps = len * 4;           // BK=64 steps per tile

  // A 32 KiB persistent | B 2 x 8 KiB double buffer = 48 KiB
  __shared__ __align__(16) char lds[49152];
  char* ldsB = lds + 32768;

  const int tid  = threadIdx.x;
  const int l    = tid & 63;
  const int wave = tid >> 6;
  const int wr   = wave >> 1;      // 64-row half
  const int wc   = wave & 1;       // 64-col half
  const int lrow = l & 15;
  const int lk   = l >> 4;

  // A read offsets for kt=3 (live all loop; kt<3 computed at one-time read)
  // chunk c = kt*4+lk, byte = row*256 + ((c ^ ((row>>1)&7))<<4)
  int offA3[4];
#pragma unroll
  for (int m = 0; m < 4; ++m) {
    const int row = wr * 64 + m * 16 + lrow;
    offA3[m] = row * 256 + (((12 + lk) ^ ((row >> 1) & 7)) << 4);
  }
  // B: chunk lk, byte = row*64 + ((lk ^ ((row>>1)&3))<<4)
  int offB[4];
#pragma unroll
  for (int n = 0; n < 4; ++n) {
    const int row = wc * 64 + n * 16 + lrow;
    offB[n] = row * 64 + ((lk ^ ((row >> 1) & 3)) << 4);
  }

  // ---- stage A panel once per strip (32 KiB = 2048 chunks, 8/thread) ----
  const unsigned char* Abase = P + (size_t)r * 128 * 256;
#pragma unroll
  for (int j = 0; j < 8; ++j) {
    const int p = tid + j * 256;          // 0..2047 (row*16 + chunk)
    const int row = p >> 4, pc = p & 15;
    __builtin_amdgcn_global_load_lds(
        (const AS1 void*)(Abase + (size_t)row * 256 +
                          ((pc ^ ((row >> 1) & 7)) << 4)),
        (AS3 void*)(lds + p * 16), 16, 0, 0);
  }

  // B staging: 8 KiB slab = 512 chunks, 2/thread, inverse-swizzled source
  auto stageB = [&](int buf, int i) {
    const int c  = cstart + (i >> 2);
    const int kb = (i & 3) * 64;          // byte offset (fp8 == 1B/elem)
    const unsigned char* B0 = Q + (size_t)c * 128 * 256 + kb;
    char* lb = ldsB + buf * 8192;
#pragma unroll
    for (int j = 0; j < 2; ++j) {
      const int p = tid + j * 256;        // 0..511 (row*4 + chunk)
      const int row = p >> 2, pc = p & 3;
      __builtin_amdgcn_global_load_lds(
          (const AS1 void*)(B0 + (size_t)row * 256 +
                            ((pc ^ ((row >> 1) & 3)) << 4)),
          (AS3 void*)(lb + p * 16), 16, 0, 0);
    }
  };
  stageB(0, 0);

  __syncthreads();                        // A panel + slab 0 staged & visible

  // ---- A fragments kt=0..2 -> 48 VGPR (one-time LDS read) ----
  longx2 afr[3][4];
#pragma unroll
  for (int kt = 0; kt < 3; ++kt)
#pragma unroll
    for (int m = 0; m < 4; ++m) {
      const int row = wr * 64 + m * 16 + lrow;
      const int off = row * 256 + (((kt * 4 + lk) ^ ((row >> 1) & 7)) << 4);
      afr[kt][m] = *(const longx2*)(lds + off);
    }

  f32x4 rsum[4];
#pragma unroll
  for (int m = 0; m < 4; ++m)
#pragma unroll
    for (int q = 0; q < 4; ++q) rsum[m][q] = 0.f;

  for (int tt = 0; tt < len; ++tt) {
    f32x4 acc[4][4];
#pragma unroll
    for (int m = 0; m < 4; ++m)
#pragma unroll
      for (int n = 0; n < 4; ++n)
#pragma unroll
        for (int q = 0; q < 4; ++q) acc[m][n][q] = 0.f;

#pragma unroll
    for (int kt = 0; kt < 4; ++kt) {
      const int i = tt * 4 + kt;
      if (i > 0) __syncthreads();          // slab i staged & prev reads done
      if (i + 1 < nsteps) stageB((i + 1) & 1, i + 1);
      const char* lb = ldsB + (i & 1) * 8192;
      longx2 bfr[4], af[4];
#pragma unroll
      for (int n = 0; n < 4; ++n)
        bfr[n] = *(const longx2*)(lb + offB[n]);
      if (kt == 3) {
#pragma unroll
        for (int m = 0; m < 4; ++m)
          af[m] = *(const longx2*)(lds + offA3[m]);
      } else {
#pragma unroll
        for (int m = 0; m < 4; ++m) af[m] = afr[kt][m];
      }
      // sub-step 0: low 8B (global slot 2lk) ; sub-step 1: high 8B (2lk+1)
#pragma unroll
      for (int m = 0; m < 4; ++m)
#pragma unroll
        for (int n = 0; n < 4; ++n)
          acc[m][n] = __builtin_amdgcn_mfma_f32_16x16x32_fp8_fp8(
              af[m][0], bfr[n][0], acc[m][n], 0, 0, 0);
#pragma unroll
      for (int m = 0; m < 4; ++m)
#pragma unroll
        for (int n = 0; n < 4; ++n)
          acc[m][n] = __builtin_amdgcn_mfma_f32_16x16x32_fp8_fp8(
              af[m][1], bfr[n][1], acc[m][n], 0, 0, 0);
    }

    // ---- tile epilogue (runs while next B slab's loads are in flight) ----
    const int c = cstart + tt;
#pragma unroll
    for (int m = 0; m < 4; ++m)
#pragma unroll
      for (int n = 0; n < 4; ++n)
#pragma unroll
        for (int q = 0; q < 4; ++q)
          acc[m][n][q] = __expf(acc[m][n][q] * INV_TAU);

#pragma unroll
    for (int m = 0; m < 4; ++m)
      rsum[m] += acc[m][0] + acc[m][1] + acc[m][2] + acc[m][3];

    const bool docol = Scol && (!sym || c > r);
    if (docol) {
#pragma unroll
      for (int n = 0; n < 4; ++n) {
        float sc = 0.f;
#pragma unroll
        for (int m = 0; m < 4; ++m)
#pragma unroll
          for (int q = 0; q < 4; ++q) sc += acc[m][n][q];
        sc += __shfl_xor(sc, 16, 64);
        sc += __shfl_xor(sc, 32, 64);
        if (l < 16) atomicAdd(&Scol[c * 128 + wc * 64 + n * 16 + l], sc);
      }
    }
  }

  // ---- strip epilogue: row sums (one atomic set per strip) ----
#pragma unroll
  for (int m = 0; m < 4; ++m) {
#pragma unroll
    for (int mask = 1; mask < 16; mask <<= 1)
#pragma unroll
      for (int q = 0; q < 4; ++q)
        rsum[m][q] += __shfl_xor(rsum[m][q], mask, 64);
    if ((l & 15) == 0) {
      const int grow = r * 128 + wr * 64 + m * 16 + lk * 4;
#pragma unroll
      for (int q = 0; q < 4; ++q) atomicAdd(&Srow[grow + q], rsum[m][q]);
    }
  }
}

// ---------------------------------------------------------------------------
// Projection GEMM: C = A @ B^T + bias, MODE 0: elu -> bf16, MODE 1: f32.
// ---------------------------------------------------------------------------
template <int MODE>
__global__ __launch_bounds__(256, 2) void proj_kernel(
    const __bf16* __restrict__ A, const __bf16* __restrict__ B,
    const float* __restrict__ bias, void* __restrict__ out)
{
  const int r = blockIdx.x, c = blockIdx.y;
  __shared__ __align__(16) char lds[32768];
  f32x4 acc[4][4];
#pragma unroll
  for (int m = 0; m < 4; ++m)
#pragma unroll
    for (int n = 0; n < 4; ++n)
#pragma unroll
      for (int q = 0; q < 4; ++q) acc[m][n][q] = 0.f;

  tile_gemm_128(A + (size_t)r * 128 * D, B + (size_t)c * 128 * D,
                lds, lds + 16384, threadIdx.x, acc);

  const int tid = threadIdx.x, l = tid & 63;
  const int wr = (tid >> 7) & 1, wc = (tid >> 6) & 1;
#pragma unroll
  for (int n = 0; n < 4; ++n) {
    const int gcol = c * 128 + wc * 64 + n * 16 + (l & 15);
    const float bn = bias[gcol];
#pragma unroll
    for (int m = 0; m < 4; ++m) {
#pragma unroll
      for (int q = 0; q < 4; ++q) {
        const int grow = r * 128 + wr * 64 + m * 16 + (l >> 4) * 4 + q;
        float v = acc[m][n][q] + bn;
        if (MODE == 0) {
          float o = v > 0.f ? v : (__expf(v) - 1.f);   // ELU
          ((__bf16*)out)[(size_t)grow * D + gcol] = (__bf16)o;
        } else {
          ((float*)out)[(size_t)grow * D + gcol] = v;
        }
      }
    }
  }
}

// ---------------------------------------------------------------------------
__global__ void cast_kernel(const float* __restrict__ src,
                            __bf16* __restrict__ dst, int n)
{
  int idx = (blockIdx.x * blockDim.x + threadIdx.x) * 4;
  const int stride = gridDim.x * blockDim.x * 4;
  for (; idx < n; idx += stride) {
    const float4 v = *(const float4*)(src + idx);
    bf16x4 o;
    o[0] = (__bf16)v.x; o[1] = (__bf16)v.y;
    o[2] = (__bf16)v.z; o[3] = (__bf16)v.w;
    *(bf16x4*)(dst + idx) = o;
  }
}

// one wave per row: L2-normalize; emits bf16 (for diag) AND fp8 e4m3 (for
// gram); padded rows written as exact zeros in both.
__global__ void norm_kernel(const float* __restrict__ praw,
                            __bf16* __restrict__ p,
                            unsigned char* __restrict__ pf)
{
  const int row = blockIdx.x * 4 + (threadIdx.x >> 6);
  const int l = threadIdx.x & 63;
  const size_t base = (size_t)row * D + l * 4;
  if (row < N_ROWS) {
    const float4 v = *(const float4*)(praw + base);
    float ss = v.x * v.x + v.y * v.y + v.z * v.z + v.w * v.w;
#pragma unroll
    for (int mask = 1; mask < 64; mask <<= 1) ss += __shfl_xor(ss, mask, 64);
    const float inv = 1.0f / fmaxf(sqrtf(ss), 1e-12f);
    const float f0 = v.x * inv, f1 = v.y * inv, f2 = v.z * inv, f3 = v.w * inv;
    bf16x4 o;
    o[0] = (__bf16)f0; o[1] = (__bf16)f1; o[2] = (__bf16)f2; o[3] = (__bf16)f3;
    *(bf16x4*)(p + base) = o;
    const unsigned int b0 = __hip_fp8_e4m3(f0).__x;
    const unsigned int b1 = __hip_fp8_e4m3(f1).__x;
    const unsigned int b2 = __hip_fp8_e4m3(f2).__x;
    const unsigned int b3 = __hip_fp8_e4m3(f3).__x;
    *(unsigned int*)(pf + base) = b0 | (b1 << 8) | (b2 << 16) | (b3 << 24);
  } else {
    bf16x4 o;
    o[0] = o[1] = o[2] = o[3] = (__bf16)0.0f;
    *(bf16x4*)(p + base) = o;
    *(unsigned int*)(pf + base) = 0u;
  }
}

// per-row diagonal terms: dg [5][NP] = exp(d11,d22,d12,d13,d23 / tau)
__global__ void diag_kernel(const __bf16* __restrict__ p1,
                            const __bf16* __restrict__ p2,
                            const __bf16* __restrict__ p3,
                            float* __restrict__ dg)
{
  const int row = blockIdx.x * 4 + (threadIdx.x >> 6);
  const int l = threadIdx.x & 63;
  if (row >= N_ROWS) return;
  const size_t base = (size_t)row * D + l * 4;
  const bf16x4 a = *(const bf16x4*)(p1 + base);
  const bf16x4 b = *(const bf16x4*)(p2 + base);
  const bf16x4 e = *(const bf16x4*)(p3 + base);
  float d11 = 0, d22 = 0, d12 = 0, d13 = 0, d23 = 0;
#pragma unroll
  for (int q = 0; q < 4; ++q) {
    const float fa = (float)a[q], fb = (float)b[q], fe = (float)e[q];
    d11 += fa * fa; d22 += fb * fb; d12 += fa * fb;
    d13 += fa * fe; d23 += fb * fe;
  }
#pragma unroll
  for (int mask = 1; mask < 64; mask <<= 1) {
    d11 += __shfl_xor(d11, mask, 64);
    d22 += __shfl_xor(d22, mask, 64);
    d12 += __shfl_xor(d12, mask, 64);
    d13 += __shfl_xor(d13, mask, 64);
    d23 += __shfl_xor(d23, mask, 64);
  }
  if (l == 0) {
    dg[0 * NP + row] = __expf(d11 * INV_TAU);
    dg[1 * NP + row] = __expf(d22 * INV_TAU);
    dg[2 * NP + row] = __expf(d12 * INV_TAU);
    dg[3 * NP + row] = __expf(d13 * INV_TAU);
    dg[4 * NP + row] = __expf(d23 * INV_TAU);
  }
}

__global__ void loss_kernel(const float* __restrict__ S,
                            const float* __restrict__ dg,
                            float* __restrict__ out)
{
  float local = 0.f;
  for (int i = blockIdx.x * blockDim.x + threadIdx.x; i < N_ROWS;
       i += gridDim.x * blockDim.x) {
    const float s11 = S[0 * NP + i] - PADF;
    const float s12 = S[1 * NP + i] - PADF;
    const float s13 = S[2 * NP + i] - PADF;
    const float s21 = S[3 * NP + i] - PADF;
    const float s22 = S[4 * NP + i] - PADF;
    const float s23 = S[5 * NP + i] - PADF;
    const float d11 = dg[0 * NP + i], d22 = dg[1 * NP + i];
    const float d12 = dg[2 * NP + i], d13 = dg[3 * NP + i];
    const float d23 = dg[4 * NP + i];
    const float den1 = s11 + s12 + s13 - d11 - d12 - d13;
    const float den2 = s22 + s21 + s23 - d22 - d12 - d23;
    local += 0.5f * (__logf(den1) + __logf(den2)) - __logf(d12);
  }
#pragma unroll
  for (int mask = 1; mask < 64; mask <<= 1) local += __shfl_xor(local, mask, 64);
  __shared__ float wsum[4];
  if ((threadIdx.x & 63) == 0) wsum[threadIdx.x >> 6] = local;
  __syncthreads();
  if (threadIdx.x == 0) {
    const float t = wsum[0] + wsum[1] + wsum[2] + wsum[3];
    atomicAdd(out, t * (1.0f / (float)N_ROWS));
  }
}

// ---------------------------------------------------------------------------
extern "C" void kernel_launch(void* const* d_in, const int* in_sizes, int n_in,
                              void* d_out, int out_size, void* d_ws,
                              size_t ws_size, hipStream_t stream)
{
  const float* z[3] = {(const float*)d_in[0], (const float*)d_in[1],
                       (const float*)d_in[2]};
  const float* W1 = (const float*)d_in[3];
  const float* b1 = (const float*)d_in[4];
  const float* W2 = (const float*)d_in[5];
  const float* b2 = (const float*)d_in[6];

  char* ws = (char*)d_ws;
  size_t off = 0;
  auto alloc = [&](size_t bytes) -> char* {
    char* p = ws + off;
    off += (bytes + 511) & ~(size_t)511;
    return p;
  };
  __bf16* pB[3];
  unsigned char* pF[3];
  for (int m = 0; m < 3; ++m) pB[m] = (__bf16*)alloc((size_t)NP * D * 2);
  for (int m = 0; m < 3; ++m) pF[m] = (unsigned char*)alloc((size_t)NP * D);
  __bf16* w1b  = (__bf16*)alloc((size_t)D * D * 2);
  __bf16* w2b  = (__bf16*)alloc((size_t)D * D * 2);
  __bf16* zb   = (__bf16*)alloc((size_t)NP * D * 2);
  __bf16* hB   = (__bf16*)alloc((size_t)NP * D * 2);
  float*  praw = (float*) alloc((size_t)NP * D * 4);
  float*  Sv   = (float*) alloc((size_t)6 * NP * 4);
  float*  dg   = (float*) alloc((size_t)5 * NP * 4);

  hipMemsetAsync(Sv, 0, (size_t)6 * NP * 4, stream);
  hipMemsetAsync(d_out, 0, sizeof(float), stream);

  cast_kernel<<<64, 256, 0, stream>>>(W1, w1b, D * D);
  cast_kernel<<<64, 256, 0, stream>>>(W2, w2b, D * D);

  for (int m = 0; m < 3; ++m) {
    cast_kernel<<<2500, 256, 0, stream>>>(z[m], zb, N_ROWS * D);
    dim3 g(PT, 2);
    proj_kernel<0><<<g, 256, 0, stream>>>(zb, w1b, b1, (void*)hB);
    proj_kernel<1><<<g, 256, 0, stream>>>(hB, w2b, b2, (void*)praw);
    norm_kernel<<<NP / 4, 256, 0, stream>>>(praw, pB[m], pF[m]);
  }

  gram_kernel<<<NWGG, 256, 0, stream>>>(pF[0], pF[1], pF[2], Sv);
  diag_kernel<<<2500, 256, 0, stream>>>(pB[0], pB[1], pB[2], dg);
  loss_kernel<<<64, 256, 0, stream>>>(Sv, dg, (float*)d_out);
}

// Round 17
// 211.304 us; speedup vs baseline: 1.9239x; 1.9239x over previous
//
#include <hip/hip_runtime.h>
#include <hip/hip_bf16.h>
#include <hip/hip_fp8.h>
#include <math.h>

#define AS1 __attribute__((address_space(1)))
#define AS3 __attribute__((address_space(3)))

typedef __bf16 bf16x8 __attribute__((ext_vector_type(8)));
typedef __bf16 bf16x4 __attribute__((ext_vector_type(4)));
typedef float  f32x4  __attribute__((ext_vector_type(4)));
typedef long   longx2 __attribute__((ext_vector_type(2)));

static constexpr int   N_ROWS   = 10000;
static constexpr int   D        = 256;           // K for all GEMMs

// gram tiling: 128x128 tiles, rows padded to 10112
static constexpr int   T        = 79;            // ceil(10000/128)
static constexpr int   NP       = T * 128;       // 10112
static constexpr float PADF     = 112.0f;        // NP - N_ROWS (exp(0)=1 each)
static constexpr int   SPR     = 10;             // strips per row (ceil(79/8))
static constexpr int   BPJ     = T * SPR;        // 790 strip-blocks per job
static constexpr int   NWGG    = 5 * BPJ;        // 3950

// proj tiling (128x128 structure)
static constexpr int   PT       = 79;

// ---------------------------------------------------------------------------
// 128x128 tile GEMM helper (projection GEMMs only, bf16). K=256, BK=64,
// single-buffer, XOR-swizzled LDS via pre-swizzled global_load_lds source.
// ---------------------------------------------------------------------------
__device__ __forceinline__ void tile_gemm_128(
    const __bf16* __restrict__ Abase, const __bf16* __restrict__ Bbase,
    char* ldsA, char* ldsB, int tid, f32x4 acc[4][4])
{
  const int l      = tid & 63;
  const int wr     = (tid >> 7) & 1;
  const int wc     = (tid >> 6) & 1;
  const int srow   = tid >> 3;
  const int schunk = tid & 7;
  const int lrow   = l & 15;
  const int lk     = l >> 4;

  for (int kt = 0; kt < 4; ++kt) {
    __syncthreads();
    const int kbase = kt * 64;
#pragma unroll
    for (int rr = 0; rr < 4; ++rr) {
      const int row = rr * 32 + srow;
      const int lc  = schunk ^ (row & 7);
      const __bf16* ga = Abase + (size_t)row * D + kbase + lc * 8;
      const __bf16* gb = Bbase + (size_t)row * D + kbase + lc * 8;
      __builtin_amdgcn_global_load_lds((const AS1 void*)ga,
          (AS3 void*)(ldsA + rr * 4096 + tid * 16), 16, 0, 0);
      __builtin_amdgcn_global_load_lds((const AS1 void*)gb,
          (AS3 void*)(ldsB + rr * 4096 + tid * 16), 16, 0, 0);
    }
    __syncthreads();
#pragma unroll
    for (int ks = 0; ks < 2; ++ks) {
      bf16x8 af[4], bfr[4];
#pragma unroll
      for (int m = 0; m < 4; ++m) {
        const int row = wr * 64 + m * 16 + lrow;
        const int off = row * 128 + ((ks * 64 + lk * 16) ^ ((row & 7) << 4));
        af[m] = *(const bf16x8*)(ldsA + off);
      }
#pragma unroll
      for (int n = 0; n < 4; ++n) {
        const int row = wc * 64 + n * 16 + lrow;
        const int off = row * 128 + ((ks * 64 + lk * 16) ^ ((row & 7) << 4));
        bfr[n] = *(const bf16x8*)(ldsB + off);
      }
#pragma unroll
      for (int m = 0; m < 4; ++m)
#pragma unroll
        for (int n = 0; n < 4; ++n)
          acc[m][n] = __builtin_amdgcn_mfma_f32_16x16x32_bf16(
              af[m], bfr[n], acc[m][n], 0, 0, 0);
    }
  }
}

// ---------------------------------------------------------------------------
// Gram kernel == r13 (proven 181us): strip-mined, FP8 e4m3, A persistent in
// LDS (32 KiB), B double-buffered BK=64 (2x8 KiB), 48 KiB -> 3 blocks/CU,
// b128 frag reads via the k-permutation trick (sub-step sub, lane lk reads
// global 8B-slot 2*lk+sub of each 64-group for BOTH operands).
// One change: pF stores p*sqrt(2), so acc == s/tau directly -> the epilogue
// drops 128 v_mul per tile (VALU was the largest pipe load, 48%).
// ---------------------------------------------------------------------------
__global__ __launch_bounds__(256, 3) void gram_kernel(
    const unsigned char* __restrict__ p1, const unsigned char* __restrict__ p2,
    const unsigned char* __restrict__ p3, float* __restrict__ S)
{
  const int bid = blockIdx.x;
  const int job = bid / BPJ;
  const int t0  = bid % BPJ;
  const int r   = t0 / SPR;
  const int s   = t0 % SPR;
  int cstart = s * 8;
  const int cend = min(cstart + 8, T);

  const unsigned char *P, *Q;
  float *Srow, *Scol;
  bool sym = false;
  if (job == 0)      { P = p1; Q = p2; Srow = S + 1 * NP; Scol = S + 3 * NP; }
  else if (job == 1) { P = p1; Q = p3; Srow = S + 2 * NP; Scol = nullptr; }
  else if (job == 2) { P = p2; Q = p3; Srow = S + 5 * NP; Scol = nullptr; }
  else if (job == 3) { P = p1; Q = p1; Srow = S + 0 * NP; Scol = S + 0 * NP;
                       sym = true; cstart = max(cstart, r); }
  else               { P = p2; Q = p2; Srow = S + 4 * NP; Scol = S + 4 * NP;
                       sym = true; cstart = max(cstart, r); }
  const int len = cend - cstart;
  if (len <= 0) return;
  const int nsteps = len * 4;           // BK=64 steps per tile

  // A 32 KiB persistent | B 2 x 8 KiB double buffer = 48 KiB
  __shared__ __align__(16) char lds[49152];
  char* ldsB = lds + 32768;

  const int tid  = threadIdx.x;
  const int l    = tid & 63;
  const int wave = tid >> 6;
  const int wr   = wave >> 1;      // 64-row half
  const int wc   = wave & 1;       // 64-col half
  const int lrow = l & 15;
  const int lk   = l >> 4;

  // Hoisted b128 read offsets.
  // A: chunk c = kt*4+lk, byte = row*256 + ((c ^ ((row>>1)&7))<<4)
  int offA[4][4];                  // [kt][m]
#pragma unroll
  for (int m = 0; m < 4; ++m) {
    const int row = wr * 64 + m * 16 + lrow;
    const int swz = (row >> 1) & 7;
#pragma unroll
    for (int kt = 0; kt < 4; ++kt)
      offA[kt][m] = row * 256 + (((kt * 4 + lk) ^ swz) << 4);
  }
  // B: chunk lk, byte = row*64 + ((lk ^ ((row>>1)&3))<<4)
  int offB[4];
#pragma unroll
  for (int n = 0; n < 4; ++n) {
    const int row = wc * 64 + n * 16 + lrow;
    offB[n] = row * 64 + ((lk ^ ((row >> 1) & 3)) << 4);
  }

  // ---- stage A panel once per strip (32 KiB = 2048 chunks, 8/thread) ----
  const unsigned char* Abase = P + (size_t)r * 128 * 256;
#pragma unroll
  for (int j = 0; j < 8; ++j) {
    const int p = tid + j * 256;          // 0..2047 (row*16 + chunk)
    const int row = p >> 4, pc = p & 15;
    __builtin_amdgcn_global_load_lds(
        (const AS1 void*)(Abase + (size_t)row * 256 +
                          ((pc ^ ((row >> 1) & 7)) << 4)),
        (AS3 void*)(lds + p * 16), 16, 0, 0);
  }

  // B staging: 8 KiB slab = 512 chunks, 2/thread, inverse-swizzled source
  auto stageB = [&](int buf, int i) {
    const int c  = cstart + (i >> 2);
    const int kb = (i & 3) * 64;          // byte offset (fp8 == 1B/elem)
    const unsigned char* B0 = Q + (size_t)c * 128 * 256 + kb;
    char* lb = ldsB + buf * 8192;
#pragma unroll
    for (int j = 0; j < 2; ++j) {
      const int p = tid + j * 256;        // 0..511 (row*4 + chunk)
      const int row = p >> 2, pc = p & 3;
      __builtin_amdgcn_global_load_lds(
          (const AS1 void*)(B0 + (size_t)row * 256 +
                            ((pc ^ ((row >> 1) & 3)) << 4)),
          (AS3 void*)(lb + p * 16), 16, 0, 0);
    }
  };
  stageB(0, 0);

  f32x4 rsum[4];
#pragma unroll
  for (int m = 0; m < 4; ++m)
#pragma unroll
    for (int q = 0; q < 4; ++q) rsum[m][q] = 0.f;

  for (int tt = 0; tt < len; ++tt) {
    f32x4 acc[4][4];
#pragma unroll
    for (int m = 0; m < 4; ++m)
#pragma unroll
      for (int n = 0; n < 4; ++n)
#pragma unroll
        for (int q = 0; q < 4; ++q) acc[m][n][q] = 0.f;

#pragma unroll
    for (int kt = 0; kt < 4; ++kt) {
      const int i = tt * 4 + kt;
      __syncthreads();                     // slab i (and A) staged & visible
      if (i + 1 < nsteps) stageB((i + 1) & 1, i + 1);
      const char* lb = ldsB + (i & 1) * 8192;
      longx2 af[4], bfr[4];
#pragma unroll
      for (int m = 0; m < 4; ++m)
        af[m] = *(const longx2*)(lds + offA[kt][m]);
#pragma unroll
      for (int n = 0; n < 4; ++n)
        bfr[n] = *(const longx2*)(lb + offB[n]);
      // sub-step 0: low 8B (global slot 2lk) ; sub-step 1: high 8B (2lk+1)
#pragma unroll
      for (int m = 0; m < 4; ++m)
#pragma unroll
        for (int n = 0; n < 4; ++n)
          acc[m][n] = __builtin_amdgcn_mfma_f32_16x16x32_fp8_fp8(
              af[m][0], bfr[n][0], acc[m][n], 0, 0, 0);
#pragma unroll
      for (int m = 0; m < 4; ++m)
#pragma unroll
        for (int n = 0; n < 4; ++n)
          acc[m][n] = __builtin_amdgcn_mfma_f32_16x16x32_fp8_fp8(
              af[m][1], bfr[n][1], acc[m][n], 0, 0, 0);
    }

    // ---- tile epilogue: acc already == s/tau (sqrt2 prescale in pF) ----
    const int c = cstart + tt;
#pragma unroll
    for (int m = 0; m < 4; ++m)
#pragma unroll
      for (int n = 0; n < 4; ++n)
#pragma unroll
        for (int q = 0; q < 4; ++q)
          acc[m][n][q] = __expf(acc[m][n][q]);

#pragma unroll
    for (int m = 0; m < 4; ++m)
      rsum[m] += acc[m][0] + acc[m][1] + acc[m][2] + acc[m][3];

    const bool docol = Scol && (!sym || c > r);
    if (docol) {
#pragma unroll
      for (int n = 0; n < 4; ++n) {
        float sc = 0.f;
#pragma unroll
        for (int m = 0; m < 4; ++m)
#pragma unroll
          for (int q = 0; q < 4; ++q) sc += acc[m][n][q];
        sc += __shfl_xor(sc, 16, 64);
        sc += __shfl_xor(sc, 32, 64);
        if (l < 16) atomicAdd(&Scol[c * 128 + wc * 64 + n * 16 + l], sc);
      }
    }
  }

  // ---- strip epilogue: row sums (one atomic set per strip) ----
#pragma unroll
  for (int m = 0; m < 4; ++m) {
#pragma unroll
    for (int mask = 1; mask < 16; mask <<= 1)
#pragma unroll
      for (int q = 0; q < 4; ++q)
        rsum[m][q] += __shfl_xor(rsum[m][q], mask, 64);
    if ((l & 15) == 0) {
      const int grow = r * 128 + wr * 64 + m * 16 + lk * 4;
#pragma unroll
      for (int q = 0; q < 4; ++q) atomicAdd(&Srow[grow + q], rsum[m][q]);
    }
  }
}

// ---------------------------------------------------------------------------
// Projection GEMM: C = A @ B^T + bias; MODE 0: elu -> bf16, MODE 1: f32.
// blockIdx.z = batch index (z1/z2/z3), offsets via strideA/strideOut elems.
// ---------------------------------------------------------------------------
template <int MODE>
__global__ __launch_bounds__(256, 2) void proj_kernel(
    const __bf16* __restrict__ A, const __bf16* __restrict__ B,
    const float* __restrict__ bias, void* __restrict__ out,
    size_t strideA, size_t strideOut)
{
  const int r = blockIdx.x, c = blockIdx.y;
  const size_t zo = (size_t)blockIdx.z;
  A += zo * strideA;
  __shared__ __align__(16) char lds[32768];
  f32x4 acc[4][4];
#pragma unroll
  for (int m = 0; m < 4; ++m)
#pragma unroll
    for (int n = 0; n < 4; ++n)
#pragma unroll
      for (int q = 0; q < 4; ++q) acc[m][n][q] = 0.f;

  tile_gemm_128(A + (size_t)r * 128 * D, B + (size_t)c * 128 * D,
                lds, lds + 16384, threadIdx.x, acc);

  const int tid = threadIdx.x, l = tid & 63;
  const int wr = (tid >> 7) & 1, wc = (tid >> 6) & 1;
#pragma unroll
  for (int n = 0; n < 4; ++n) {
    const int gcol = c * 128 + wc * 64 + n * 16 + (l & 15);
    const float bn = bias[gcol];
#pragma unroll
    for (int m = 0; m < 4; ++m) {
#pragma unroll
      for (int q = 0; q < 4; ++q) {
        const int grow = r * 128 + wr * 64 + m * 16 + (l >> 4) * 4 + q;
        float v = acc[m][n][q] + bn;
        if (MODE == 0) {
          float o = v > 0.f ? v : (__expf(v) - 1.f);   // ELU
          ((__bf16*)out)[zo * strideOut + (size_t)grow * D + gcol] = (__bf16)o;
        } else {
          ((float*)out)[zo * strideOut + (size_t)grow * D + gcol] = v;
        }
      }
    }
  }
}

// ---------------------------------------------------------------------------
__global__ void cast_kernel(const float* __restrict__ src,
                            __bf16* __restrict__ dst, int n)
{
  int idx = (blockIdx.x * blockDim.x + threadIdx.x) * 4;
  const int stride = gridDim.x * blockDim.x * 4;
  for (; idx < n; idx += stride) {
    const float4 v = *(const float4*)(src + idx);
    bf16x4 o;
    o[0] = (__bf16)v.x; o[1] = (__bf16)v.y;
    o[2] = (__bf16)v.z; o[3] = (__bf16)v.w;
    *(bf16x4*)(dst + idx) = o;
  }
}

// batched: casts z0/z1/z2 (N_ROWS*D f32 each) into dst + m*strideElems
__global__ void cast3_kernel(const float* __restrict__ z0,
                             const float* __restrict__ z1,
                             const float* __restrict__ z2,
                             __bf16* __restrict__ dst, size_t strideElems)
{
  const int n = N_ROWS * D;
  int idx = (blockIdx.x * blockDim.x + threadIdx.x) * 4;
  const int stride = gridDim.x * blockDim.x * 4;
  for (; idx < 3 * n; idx += stride) {
    const int m = idx / n, e = idx - m * n;
    const float* src = (m == 0) ? z0 : (m == 1) ? z1 : z2;
    const float4 v = *(const float4*)(src + e);
    bf16x4 o;
    o[0] = (__bf16)v.x; o[1] = (__bf16)v.y;
    o[2] = (__bf16)v.z; o[3] = (__bf16)v.w;
    *(bf16x4*)(dst + m * strideElems + e) = o;
  }
}

// one wave per row: L2-normalize; emits bf16 (for diag) AND fp8 e4m3*sqrt(2)
// (for gram -- folds 1/tau into the MFMA inputs); padded rows exact zeros.
// blockIdx.y = batch index; each input/output offset by y*NP*D elems.
__global__ void norm_kernel(const float* __restrict__ praw,
                            __bf16* __restrict__ p,
                            unsigned char* __restrict__ pf)
{
  const size_t mo = (size_t)blockIdx.y * NP * D;
  const int row = blockIdx.x * 4 + (threadIdx.x >> 6);
  const int l = threadIdx.x & 63;
  const size_t base = mo + (size_t)row * D + l * 4;
  if (row < N_ROWS) {
    const float4 v = *(const float4*)(praw + base);
    float ss = v.x * v.x + v.y * v.y + v.z * v.z + v.w * v.w;
#pragma unroll
    for (int mask = 1; mask < 64; mask <<= 1) ss += __shfl_xor(ss, mask, 64);
    const float inv = 1.0f / fmaxf(sqrtf(ss), 1e-12f);
    const float f0 = v.x * inv, f1 = v.y * inv, f2 = v.z * inv, f3 = v.w * inv;
    bf16x4 o;
    o[0] = (__bf16)f0; o[1] = (__bf16)f1; o[2] = (__bf16)f2; o[3] = (__bf16)f3;
    *(bf16x4*)(p + base) = o;
    const float SC = 1.41421356237f;     // sqrt(1/tau) with tau=0.5
    const unsigned int b0 = __hip_fp8_e4m3(f0 * SC).__x;
    const unsigned int b1 = __hip_fp8_e4m3(f1 * SC).__x;
    const unsigned int b2 = __hip_fp8_e4m3(f2 * SC).__x;
    const unsigned int b3 = __hip_fp8_e4m3(f3 * SC).__x;
    *(unsigned int*)(pf + base) = b0 | (b1 << 8) | (b2 << 16) | (b3 << 24);
  } else {
    bf16x4 o;
    o[0] = o[1] = o[2] = o[3] = (__bf16)0.0f;
    *(bf16x4*)(p + base) = o;
    *(unsigned int*)(pf + base) = 0u;
  }
}

// per-row diagonal terms: dg [5][NP] = exp(d11,d22,d12,d13,d23 / tau)
__global__ void diag_kernel(const __bf16* __restrict__ p1,
                            const __bf16* __restrict__ p2,
                            const __bf16* __restrict__ p3,
                            float* __restrict__ dg)
{
  const int row = blockIdx.x * 4 + (threadIdx.x >> 6);
  const int l = threadIdx.x & 63;
  if (row >= N_ROWS) return;
  const size_t base = (size_t)row * D + l * 4;
  const bf16x4 a = *(const bf16x4*)(p1 + base);
  const bf16x4 b = *(const bf16x4*)(p2 + base);
  const bf16x4 e = *(const bf16x4*)(p3 + base);
  float d11 = 0, d22 = 0, d12 = 0, d13 = 0, d23 = 0;
#pragma unroll
  for (int q = 0; q < 4; ++q) {
    const float fa = (float)a[q], fb = (float)b[q], fe = (float)e[q];
    d11 += fa * fa; d22 += fb * fb; d12 += fa * fb;
    d13 += fa * fe; d23 += fb * fe;
  }
#pragma unroll
  for (int mask = 1; mask < 64; mask <<= 1) {
    d11 += __shfl_xor(d11, mask, 64);
    d22 += __shfl_xor(d22, mask, 64);
    d12 += __shfl_xor(d12, mask, 64);
    d13 += __shfl_xor(d13, mask, 64);
    d23 += __shfl_xor(d23, mask, 64);
  }
  if (l == 0) {
    dg[0 * NP + row] = __expf(d11 * 2.0f);
    dg[1 * NP + row] = __expf(d22 * 2.0f);
    dg[2 * NP + row] = __expf(d12 * 2.0f);
    dg[3 * NP + row] = __expf(d13 * 2.0f);
    dg[4 * NP + row] = __expf(d23 * 2.0f);
  }
}

__global__ void loss_kernel(const float* __restrict__ S,
                            const float* __restrict__ dg,
                            float* __restrict__ out)
{
  float local = 0.f;
  for (int i = blockIdx.x * blockDim.x + threadIdx.x; i < N_ROWS;
       i += gridDim.x * blockDim.x) {
    const float s11 = S[0 * NP + i] - PADF;
    const float s12 = S[1 * NP + i] - PADF;
    const float s13 = S[2 * NP + i] - PADF;
    const float s21 = S[3 * NP + i] - PADF;
    const float s22 = S[4 * NP + i] - PADF;
    const float s23 = S[5 * NP + i] - PADF;
    const float d11 = dg[0 * NP + i], d22 = dg[1 * NP + i];
    const float d12 = dg[2 * NP + i], d13 = dg[3 * NP + i];
    const float d23 = dg[4 * NP + i];
    const float den1 = s11 + s12 + s13 - d11 - d12 - d13;
    const float den2 = s22 + s21 + s23 - d22 - d12 - d23;
    local += 0.5f * (__logf(den1) + __logf(den2)) - __logf(d12);
  }
#pragma unroll
  for (int mask = 1; mask < 64; mask <<= 1) local += __shfl_xor(local, mask, 64);
  __shared__ float wsum[4];
  if ((threadIdx.x & 63) == 0) wsum[threadIdx.x >> 6] = local;
  __syncthreads();
  if (threadIdx.x == 0) {
    const float t = wsum[0] + wsum[1] + wsum[2] + wsum[3];
    atomicAdd(out, t * (1.0f / (float)N_ROWS));
  }
}

// ---------------------------------------------------------------------------
extern "C" void kernel_launch(void* const* d_in, const int* in_sizes, int n_in,
                              void* d_out, int out_size, void* d_ws,
                              size_t ws_size, hipStream_t stream)
{
  const float* z[3] = {(const float*)d_in[0], (const float*)d_in[1],
                       (const float*)d_in[2]};
  const float* W1 = (const float*)d_in[3];
  const float* b1 = (const float*)d_in[4];
  const float* W2 = (const float*)d_in[5];
  const float* b2 = (const float*)d_in[6];

  char* ws = (char*)d_ws;
  size_t off = 0;
  auto alloc = [&](size_t bytes) -> char* {
    char* p = ws + off;
    off += (bytes + 511) & ~(size_t)511;
    return p;
  };
  const size_t PE = (size_t)NP * D;               // elems per panel
  // common buffers
  __bf16*        pB3 = (__bf16*)alloc(3 * PE * 2);
  unsigned char* pF3 = (unsigned char*)alloc(3 * PE);
  __bf16* w1b  = (__bf16*)alloc((size_t)D * D * 2);
  __bf16* w2b  = (__bf16*)alloc((size_t)D * D * 2);
  float*  Sv   = (float*) alloc((size_t)6 * NP * 4);
  float*  dg   = (float*) alloc((size_t)5 * NP * 4);

  // batched path needs 3x zb/hB/praw; fall back to sequential if ws is small
  const size_t common = off;
  const size_t batched_need = common + 3 * ((PE * 2 + 511 & ~511ull) +
                              (PE * 2 + 511 & ~511ull)) + 3 * (PE * 4) + 4096;
  const bool batched = ws_size >= batched_need;

  hipMemsetAsync(Sv, 0, (size_t)6 * NP * 4, stream);
  hipMemsetAsync(d_out, 0, sizeof(float), stream);

  cast_kernel<<<64, 256, 0, stream>>>(W1, w1b, D * D);
  cast_kernel<<<64, 256, 0, stream>>>(W2, w2b, D * D);

  if (batched) {
    __bf16* zb3   = (__bf16*)alloc(3 * PE * 2);
    __bf16* hB3   = (__bf16*)alloc(3 * PE * 2);
    float*  praw3 = (float*) alloc(3 * PE * 4);
    cast3_kernel<<<2048, 256, 0, stream>>>(z[0], z[1], z[2], zb3, PE);
    dim3 g(PT, 2, 3);
    proj_kernel<0><<<g, 256, 0, stream>>>(zb3, w1b, b1, (void*)hB3, PE, PE);
    proj_kernel<1><<<g, 256, 0, stream>>>(hB3, w2b, b2, (void*)praw3, PE, PE);
    dim3 gn(NP / 4, 3);
    norm_kernel<<<gn, 256, 0, stream>>>(praw3, pB3, pF3);
  } else {
    __bf16* zb   = (__bf16*)alloc(PE * 2);
    __bf16* hB   = (__bf16*)alloc(PE * 2);
    float*  praw = (float*) alloc(PE * 4);
    for (int m = 0; m < 3; ++m) {
      cast_kernel<<<2500, 256, 0, stream>>>(z[m], zb, N_ROWS * D);
      dim3 g(PT, 2, 1);
      proj_kernel<0><<<g, 256, 0, stream>>>(zb, w1b, b1, (void*)hB, 0, 0);
      proj_kernel<1><<<g, 256, 0, stream>>>(hB, w2b, b2, (void*)praw, 0, 0);
      dim3 gn(NP / 4, 1);
      norm_kernel<<<gn, 256, 0, stream>>>(praw, pB3 + m * PE, pF3 + m * PE);
    }
  }

  gram_kernel<<<NWGG, 256, 0, stream>>>(pF3, pF3 + PE, pF3 + 2 * PE, Sv);
  diag_kernel<<<2500, 256, 0, stream>>>(pB3, pB3 + PE, pB3 + 2 * PE, dg);
  loss_kernel<<<64, 256, 0, stream>>>(Sv, dg, (float*)d_out);
}